// Round 1
// baseline (1223.865 us; speedup 1.0000x reference)
//
#include <hip/hip_runtime.h>
#include <hip/hip_bf16.h>
#include <cmath>

// Problem constants
#define B_SZ 8
#define L_SZ 2048
#define D_SZ 1024
#define CH 341
#define CHP 344              // padded channel dim (mult of 8, 16B-aligned rows)
#define LCONV 2046           // L - KERNEL + 1
#define NSEG 512

// Output layout (floats): pooled[8*512*1024], num_boundaries[1], total_positions[1], short_mask[8*512]
#define POOLED_N (B_SZ * NSEG * D_SZ)

// ---------------------------------------------------------------------------
// K0: transpose w1 (Ch,D,K) -> w1t[k][d][c_padded] (zeros in pad), init logits
//     to b2, zero the two scalar outputs.
// ---------------------------------------------------------------------------
__global__ void init_kernel(const float* __restrict__ w1, const float* __restrict__ b2,
                            float* __restrict__ w1t, float* __restrict__ logits,
                            float* __restrict__ out_scalars) {
    int idx = blockIdx.x * 256 + threadIdx.x;
    const int W1T = 3 * 1024 * CHP;
    if (idx < W1T) {
        int kk = idx / (1024 * CHP);
        int rem = idx - kk * (1024 * CHP);
        int d = rem / CHP;
        int c = rem - d * CHP;
        w1t[idx] = (c < CH) ? w1[((size_t)c * D_SZ + d) * 3 + kk] : 0.0f;
    }
    if (idx < B_SZ * LCONV) logits[idx] = b2[0];
    if (idx == 0) { out_scalars[0] = 0.0f; out_scalars[1] = 0.0f; }
}

// ---------------------------------------------------------------------------
// K1: fp32 GEMM conv + fused relu(h+b1)*w2 epilogue, atomicAdd partial c-sums
//     into logits (initialized to b2).
//     Block tile 64 l x 64 c, BK=32, 256 threads, 4x4 micro-tile.
// ---------------------------------------------------------------------------
__global__ __launch_bounds__(256) void conv_gemm_kernel(
        const float* __restrict__ hidden, const float* __restrict__ w1t,
        const float* __restrict__ b1, const float* __restrict__ w2,
        float* __restrict__ logits) {
    const int b  = blockIdx.z;
    const int l0 = blockIdx.x * 64;
    const int c0 = blockIdx.y * 64;
    const int tid = threadIdx.x;
    const int ti = tid & 15;   // l micro index
    const int tj = tid >> 4;   // c micro index

    __shared__ __align__(16) float As[32][68];  // [k][l]  (transposed for b128 reads)
    __shared__ __align__(16) float Bs[32][68];  // [k][c]

    float acc[4][4] = {};
    const float* hb = hidden + (size_t)b * L_SZ * D_SZ;

    for (int kk = 0; kk < 3; ++kk) {
        for (int d0 = 0; d0 < 1024; d0 += 32) {
            // stage A: 64 l x 32 d
            #pragma unroll
            for (int p = 0; p < 2; ++p) {
                int flat = p * 256 + tid;
                int i = flat >> 3, jf = (flat & 7) << 2;
                float4 v = make_float4(0.f, 0.f, 0.f, 0.f);
                if (l0 + i < LCONV)
                    v = *(const float4*)(hb + (size_t)(l0 + i + kk) * D_SZ + d0 + jf);
                As[jf + 0][i] = v.x; As[jf + 1][i] = v.y;
                As[jf + 2][i] = v.z; As[jf + 3][i] = v.w;
            }
            // stage B: 32 d x 64 c
            #pragma unroll
            for (int p = 0; p < 2; ++p) {
                int flat = p * 256 + tid;
                int j = flat >> 4, cf = (flat & 15) << 2;
                float4 v = make_float4(0.f, 0.f, 0.f, 0.f);
                if (c0 + cf <= CH - 1)   // reads up to c0+cf+3 <= 343, inside pad
                    v = *(const float4*)(w1t + (size_t)kk * 1024 * CHP +
                                         (size_t)(d0 + j) * CHP + c0 + cf);
                *(float4*)&Bs[j][cf] = v;
            }
            __syncthreads();
            #pragma unroll
            for (int j = 0; j < 32; ++j) {
                float4 a  = *(const float4*)&As[j][ti * 4];
                float4 bb = *(const float4*)&Bs[j][tj * 4];
                float av[4] = {a.x, a.y, a.z, a.w};
                float bv[4] = {bb.x, bb.y, bb.z, bb.w};
                #pragma unroll
                for (int r = 0; r < 4; ++r)
                    #pragma unroll
                    for (int c = 0; c < 4; ++c)
                        acc[r][c] += av[r] * bv[c];
            }
            __syncthreads();
        }
    }

    // epilogue: relu(h + b1)*w2, reduce over this block's 64 c, atomic into logits
    float part[4];
    #pragma unroll
    for (int r = 0; r < 4; ++r) {
        float p = 0.f;
        #pragma unroll
        for (int c4 = 0; c4 < 4; ++c4) {
            int c = c0 + tj * 4 + c4;
            if (c < CH) {
                float h = acc[r][c4] + b1[c];
                if (h > 0.0f) p += h * w2[c];
            }
        }
        part[r] = p;
    }
    __syncthreads();
    float (*red)[17] = (float (*)[17])&As[0][0];
    #pragma unroll
    for (int r = 0; r < 4; ++r) red[ti * 4 + r][tj] = part[r];
    __syncthreads();
    if (tid < 64) {
        float ssum = 0.f;
        #pragma unroll
        for (int t = 0; t < 16; ++t) ssum += red[tid][t];
        if (l0 + tid < LCONV)
            atomicAdd(&logits[b * LCONV + l0 + tid], ssum);
    }
}

// ---------------------------------------------------------------------------
// K2: per-row boundary scan. hard[l] = (l>=2 && l<len && logit[l-2]>0) | forced
//     at len-1 (if len<L). Segments are contiguous runs -> emit 513 start
//     offsets per row. Also writes short_mask and the two scalar outputs.
// ---------------------------------------------------------------------------
__global__ void boundary_scan_kernel(const float* __restrict__ logits,
                                     const float* __restrict__ amask,
                                     int* __restrict__ segstart,
                                     float* __restrict__ out_nb,
                                     float* __restrict__ out_tp,
                                     float* __restrict__ short_mask) {
    const int b = blockIdx.x, tid = threadIdx.x;
    __shared__ int sdata[256];
    __shared__ int s_len, s_total;

    // sequence length = sum(mask)
    int cnt = 0;
    #pragma unroll
    for (int j = 0; j < 8; ++j) {
        int l = tid * 8 + j;
        cnt += (amask[b * L_SZ + l] > 0.5f) ? 1 : 0;
    }
    sdata[tid] = cnt; __syncthreads();
    for (int off = 128; off > 0; off >>= 1) {
        if (tid < off) sdata[tid] += sdata[tid + off];
        __syncthreads();
    }
    if (tid == 0) s_len = sdata[0];
    __syncthreads();
    const int len = s_len;

    // hard bits (8 per thread)
    int bits[8]; int tsum = 0;
    #pragma unroll
    for (int j = 0; j < 8; ++j) {
        int l = tid * 8 + j;
        int h = 0;
        if (l >= 2 && l < len) h = (logits[b * LCONV + (l - 2)] > 0.0f) ? 1 : 0;
        if (len < L_SZ && l == len - 1) h = 1;   // forced boundary at last real token
        bits[j] = h; tsum += h;
    }
    __syncthreads();
    sdata[tid] = tsum; __syncthreads();
    for (int off = 1; off < 256; off <<= 1) {    // Hillis-Steele inclusive scan
        int v = (tid >= off) ? sdata[tid - off] : 0;
        __syncthreads();
        sdata[tid] += v;
        __syncthreads();
    }
    const int texcl = sdata[tid] - tsum;
    if (tid == 255) s_total = sdata[255];
    __syncthreads();
    const int total = s_total;

    // segment starts: start[0]=0, start[r+1]=boundary_pos_r+1, rest=len
    for (int s = tid; s <= NSEG; s += 256)
        segstart[b * (NSEG + 1) + s] = (s == 0) ? 0 : len;
    __syncthreads();
    int run = texcl;
    #pragma unroll
    for (int j = 0; j < 8; ++j) {
        int l = tid * 8 + j;
        if (bits[j]) {
            if (run + 1 <= NSEG) segstart[b * (NSEG + 1) + run + 1] = l + 1;
            run++;
        }
    }

    if (tid == 0) {
        atomicAdd(out_nb, (float)total);
        atomicAdd(out_tp, (float)len);
    }
    for (int s = tid; s < NSEG; s += 256)
        short_mask[b * NSEG + s] = (s < total) ? 1.0f : 0.0f;
}

// ---------------------------------------------------------------------------
// K3: segmented mean pool + sinusoidal PE. One 64-thread block per
//     (segment, d-quarter, batch); threads cover 256 d's via float4.
// ---------------------------------------------------------------------------
__global__ void pool_kernel(const float* __restrict__ hidden,
                            const int* __restrict__ segstart,
                            float* __restrict__ pooled) {
    const int s = blockIdx.x, dq = blockIdx.y, b = blockIdx.z;
    const int tid = threadIdx.x;
    const int d0 = dq * 256 + tid * 4;

    const int l0 = segstart[b * (NSEG + 1) + s];
    const int l1 = segstart[b * (NSEG + 1) + s + 1];

    float4 acc = make_float4(0.f, 0.f, 0.f, 0.f);
    const float* base = hidden + (size_t)b * L_SZ * D_SZ + d0;
    for (int l = l0; l < l1; ++l) {
        float4 v = *(const float4*)(base + (size_t)l * D_SZ);
        acc.x += v.x; acc.y += v.y; acc.z += v.z; acc.w += v.w;
    }
    const float inv = 1.0f / ((float)(l1 - l0) + 1e-9f);

    // PE: even d -> sin(s * 10000^{-i/512}), odd d -> cos(same), i = d/2
    const float ce = -9.210340371976184f / 512.0f;   // -ln(10000)/512
    const int i = d0 >> 1;
    const float ang0 = (float)s * expf(ce * (float)i);
    const float ang1 = (float)s * expf(ce * (float)(i + 1));
    float4 o;
    o.x = acc.x * inv + sinf(ang0);
    o.y = acc.y * inv + cosf(ang0);
    o.z = acc.z * inv + sinf(ang1);
    o.w = acc.w * inv + cosf(ang1);
    *(float4*)(pooled + ((size_t)(b * NSEG + s)) * D_SZ + d0) = o;
}

// ---------------------------------------------------------------------------
extern "C" void kernel_launch(void* const* d_in, const int* in_sizes, int n_in,
                              void* d_out, int out_size, void* d_ws, size_t ws_size,
                              hipStream_t stream) {
    const float* hidden = (const float*)d_in[0];
    const float* amask  = (const float*)d_in[1];
    const float* w1     = (const float*)d_in[2];
    const float* b1     = (const float*)d_in[3];
    const float* w2     = (const float*)d_in[4];
    const float* b2     = (const float*)d_in[5];

    float* out    = (float*)d_out;
    float* pooled = out;
    float* nb     = out + POOLED_N;        // num_boundaries
    // tp = nb + 1 (contiguous, init_kernel zeroes both)
    float* smask  = out + POOLED_N + 2;

    float* w1t      = (float*)d_ws;                    // 3*1024*344 floats
    float* logits   = w1t + 3 * 1024 * CHP;            // 8*2046 floats
    int*   segstart = (int*)(logits + B_SZ * LCONV);   // 8*513 ints

    init_kernel<<<(3 * 1024 * CHP + 255) / 256, 256, 0, stream>>>(w1, b2, w1t, logits, nb);
    conv_gemm_kernel<<<dim3(32, 6, B_SZ), 256, 0, stream>>>(hidden, w1t, b1, w2, logits);
    boundary_scan_kernel<<<B_SZ, 256, 0, stream>>>(logits, amask, segstart, nb, nb + 1, smask);
    pool_kernel<<<dim3(NSEG, 4, B_SZ), 64, 0, stream>>>(hidden, segstart, pooled);
}

// Round 2
// 398.948 us; speedup vs baseline: 3.0677x; 3.0677x over previous
//
#include <hip/hip_runtime.h>
#include <hip/hip_bf16.h>
#include <cmath>

// Problem constants
#define B_SZ 8
#define L_SZ 2048
#define D_SZ 1024
#define CH 341
#define CHP 344              // padded channel dim for fp32 fallback path
#define CP 384               // padded channel dim for MFMA path (6 x 64)
#define LCONV 2046           // L - KERNEL + 1
#define NSEG 512
#define KDIM 3072            // 3 * 1024 folded conv K

#define POOLED_N (B_SZ * NSEG * D_SZ)

typedef unsigned short ushort_t;
typedef __bf16 bf16x8 __attribute__((ext_vector_type(8)));
typedef float f32x4 __attribute__((ext_vector_type(4)));

// ---------------------------------------------------------------------------
// helpers
// ---------------------------------------------------------------------------
__device__ __forceinline__ ushort_t f2bf(float f) {
    unsigned u = __float_as_uint(f);
    return (ushort_t)((u + 0x7fffu + ((u >> 16) & 1u)) >> 16);
}
__device__ __forceinline__ float bf2f(ushort_t b) {
    return __uint_as_float(((unsigned)b) << 16);
}
__device__ __forceinline__ void gl_lds16(const void* g, void* l) {
    __builtin_amdgcn_global_load_lds(
        (const __attribute__((address_space(1))) unsigned int*)g,
        (__attribute__((address_space(3))) unsigned int*)l, 16, 0, 0);
}

// ---------------------------------------------------------------------------
// Convert hidden fp32 -> bf16 hi + lo (split precision)
// ---------------------------------------------------------------------------
__global__ __launch_bounds__(256) void convert_hidden_kernel(
        const float* __restrict__ hidden,
        ushort_t* __restrict__ hi, ushort_t* __restrict__ lo) {
    int idx = blockIdx.x * 256 + threadIdx.x;   // one float4 per thread
    float4 v = ((const float4*)hidden)[idx];
    ushort4 h, l;
    h.x = f2bf(v.x); l.x = f2bf(v.x - bf2f(h.x));
    h.y = f2bf(v.y); l.y = f2bf(v.y - bf2f(h.y));
    h.z = f2bf(v.z); l.z = f2bf(v.z - bf2f(h.z));
    h.w = f2bf(v.w); l.w = f2bf(v.w - bf2f(h.w));
    ((ushort4*)hi)[idx] = h;
    ((ushort4*)lo)[idx] = l;
}

// ---------------------------------------------------------------------------
// Convert w1 (Ch,D,K) -> w1b[c][k'=kk*1024+d] bf16 hi/lo, c padded to 384.
// Also init logits to b2.
// ---------------------------------------------------------------------------
__global__ __launch_bounds__(256) void convert_w1_kernel(
        const float* __restrict__ w1, const float* __restrict__ b2,
        ushort_t* __restrict__ whi, ushort_t* __restrict__ wlo,
        float* __restrict__ logits) {
    int idx = blockIdx.x * 256 + threadIdx.x;   // < 384*3072
    int c = idx / KDIM;
    int kp = idx - c * KDIM;
    int kk = kp >> 10, d = kp & 1023;
    float v = (c < CH) ? w1[((size_t)c * 1024 + d) * 3 + kk] : 0.0f;
    ushort_t h = f2bf(v);
    whi[idx] = h;
    wlo[idx] = f2bf(v - bf2f(h));
    if (idx < B_SZ * LCONV) logits[idx] = b2[0];
}

// ---------------------------------------------------------------------------
// MFMA conv GEMM: per batch, M=2046(l) x N=384(c) x K=3072, bf16x3 split.
// Block tile 128(l) x 64(c), 4 waves, wave tile 64x32 (4x2 16x16 frags).
// LDS tiles stored in *fragment order* -> conflict-free ds_read_b128.
// Fused epilogue: relu(h+b1)*w2 reduced over c, atomicAdd into logits.
// ---------------------------------------------------------------------------
#define LDS_AHI 0
#define LDS_ALO 8192
#define LDS_BHI 16384
#define LDS_BLO 20480

__global__ __launch_bounds__(256) void conv_mfma_kernel(
        const ushort_t* __restrict__ hid_hi, const ushort_t* __restrict__ hid_lo,
        const ushort_t* __restrict__ w1b_hi, const ushort_t* __restrict__ w1b_lo,
        const float* __restrict__ b1, const float* __restrict__ w2,
        float* __restrict__ logits) {
    const int nt = blockIdx.x;           // 0..5   c-tile (fastest: A reuse in L2)
    const int mt = blockIdx.y;           // 0..15  l-tile
    const int b  = blockIdx.z;
    const int c0 = nt * 64;
    const int l0 = mt * 128;
    const int tid = threadIdx.x;
    const int wave = tid >> 6, lane = tid & 63;
    const int wm = wave & 1, wn = wave >> 1;
    const int quad = lane >> 4, l16 = lane & 15;

    __shared__ __align__(16) char lds[24576];

    const ushort_t* hb_hi = hid_hi + (size_t)b * L_SZ * D_SZ;
    const ushort_t* hb_lo = hid_lo + (size_t)b * L_SZ * D_SZ;

    // --- per-lane staging source pointers ---
    // A entries f in [0,512): m = (f>>6)*16 + (f&15), kc = (f>>4)&3
    int fA0 = wave * 128 + lane;
    int fA1 = fA0 + 64;
    int mA0 = ((fA0 >> 6) << 4) + (fA0 & 15);
    int mA1 = ((fA1 >> 6) << 4) + (fA1 & 15);
    int lA0 = l0 + mA0; if (lA0 > LCONV - 1) lA0 = LCONV - 1;
    int lA1 = l0 + mA1; if (lA1 > LCONV - 1) lA1 = LCONV - 1;
    size_t offA0 = (size_t)lA0 * 1024 + ((fA0 >> 4) & 3) * 8;
    size_t offA1 = (size_t)lA1 * 1024 + ((fA1 >> 4) & 3) * 8;
    const ushort_t* pAhi0 = hb_hi + offA0;
    const ushort_t* pAhi1 = hb_hi + offA1;
    const ushort_t* pAlo0 = hb_lo + offA0;
    const ushort_t* pAlo1 = hb_lo + offA1;
    // B entries f in [0,256): n = (f>>6)*16 + (f&15) = wave*16 + l16
    int nB = wave * 16 + l16;
    size_t offB = (size_t)(c0 + nB) * KDIM + quad * 8;
    const ushort_t* pBhi = w1b_hi + offB;
    const ushort_t* pBlo = w1b_lo + offB;

    char* ldsAhi_w0 = lds + LDS_AHI + wave * 2048;
    char* ldsAhi_w1 = ldsAhi_w0 + 1024;
    char* ldsAlo_w0 = lds + LDS_ALO + wave * 2048;
    char* ldsAlo_w1 = ldsAlo_w0 + 1024;
    char* ldsBhi_w  = lds + LDS_BHI + wave * 1024;
    char* ldsBlo_w  = lds + LDS_BLO + wave * 1024;

    f32x4 acc[4][2] = {};

    for (int step = 0; step < KDIM / 32; ++step) {
        gl_lds16(pAhi0, ldsAhi_w0);
        gl_lds16(pAhi1, ldsAhi_w1);
        gl_lds16(pAlo0, ldsAlo_w0);
        gl_lds16(pAlo1, ldsAlo_w1);
        gl_lds16(pBhi,  ldsBhi_w);
        gl_lds16(pBlo,  ldsBlo_w);
        pAhi0 += 32; pAhi1 += 32; pAlo0 += 32; pAlo1 += 32;
        pBhi  += 32; pBlo  += 32;
        __syncthreads();

        bf16x8 ahi[4], alo[4], bhi[2], blo[2];
        #pragma unroll
        for (int i = 0; i < 4; ++i) {
            int e = ((wm * 4 + i) * 64 + lane) * 16;
            ahi[i] = *(const bf16x8*)(lds + LDS_AHI + e);
            alo[i] = *(const bf16x8*)(lds + LDS_ALO + e);
        }
        #pragma unroll
        for (int j = 0; j < 2; ++j) {
            int e = ((wn * 2 + j) * 64 + lane) * 16;
            bhi[j] = *(const bf16x8*)(lds + LDS_BHI + e);
            blo[j] = *(const bf16x8*)(lds + LDS_BLO + e);
        }
        #pragma unroll
        for (int i = 0; i < 4; ++i)
            #pragma unroll
            for (int j = 0; j < 2; ++j) {
                acc[i][j] = __builtin_amdgcn_mfma_f32_16x16x32_bf16(ahi[i], bhi[j], acc[i][j], 0, 0, 0);
                acc[i][j] = __builtin_amdgcn_mfma_f32_16x16x32_bf16(ahi[i], blo[j], acc[i][j], 0, 0, 0);
                acc[i][j] = __builtin_amdgcn_mfma_f32_16x16x32_bf16(alo[i], bhi[j], acc[i][j], 0, 0, 0);
            }
        __syncthreads();
    }

    // --- epilogue: relu(acc + b1)*w2, reduce over c, atomic into logits ---
    float c_b1[2], c_w2[2];
    #pragma unroll
    for (int j = 0; j < 2; ++j) {
        int c = c0 + wn * 32 + j * 16 + l16;
        bool v = c < CH;
        c_b1[j] = v ? b1[c] : 0.0f;
        c_w2[j] = v ? w2[c] : 0.0f;
    }
    float* red = (float*)lds;   // [128][2], reuses A-tile space (post-loop sync done)
    #pragma unroll
    for (int i = 0; i < 4; ++i)
        #pragma unroll
        for (int r = 0; r < 4; ++r) {
            float pp = 0.0f;
            #pragma unroll
            for (int j = 0; j < 2; ++j) {
                float h = acc[i][j][r] + c_b1[j];
                if (h > 0.0f) pp += h * c_w2[j];
            }
            pp += __shfl_xor(pp, 1);
            pp += __shfl_xor(pp, 2);
            pp += __shfl_xor(pp, 4);
            pp += __shfl_xor(pp, 8);
            if (l16 == 0)
                red[(wm * 64 + i * 16 + quad * 4 + r) * 2 + wn] = pp;
        }
    __syncthreads();
    if (tid < 128) {
        int l = l0 + tid;
        if (l < LCONV)
            atomicAdd(&logits[b * LCONV + l], red[tid * 2] + red[tid * 2 + 1]);
    }
}

// ---------------------------------------------------------------------------
// Fallback fp32 path (round-1 kernels), used only if ws is too small
// ---------------------------------------------------------------------------
__global__ void init_kernel(const float* __restrict__ w1, const float* __restrict__ b2,
                            float* __restrict__ w1t, float* __restrict__ logits) {
    int idx = blockIdx.x * 256 + threadIdx.x;
    const int W1T = 3 * 1024 * CHP;
    if (idx < W1T) {
        int kk = idx / (1024 * CHP);
        int rem = idx - kk * (1024 * CHP);
        int d = rem / CHP;
        int c = rem - d * CHP;
        w1t[idx] = (c < CH) ? w1[((size_t)c * D_SZ + d) * 3 + kk] : 0.0f;
    }
    if (idx < B_SZ * LCONV) logits[idx] = b2[0];
}

__global__ __launch_bounds__(256) void conv_gemm_kernel(
        const float* __restrict__ hidden, const float* __restrict__ w1t,
        const float* __restrict__ b1, const float* __restrict__ w2,
        float* __restrict__ logits) {
    const int b  = blockIdx.z;
    const int l0 = blockIdx.x * 64;
    const int c0 = blockIdx.y * 64;
    const int tid = threadIdx.x;
    const int ti = tid & 15;
    const int tj = tid >> 4;

    __shared__ __align__(16) float As[32][68];
    __shared__ __align__(16) float Bs[32][68];

    float acc[4][4] = {};
    const float* hb = hidden + (size_t)b * L_SZ * D_SZ;

    for (int kk = 0; kk < 3; ++kk) {
        for (int d0 = 0; d0 < 1024; d0 += 32) {
            #pragma unroll
            for (int p = 0; p < 2; ++p) {
                int flat = p * 256 + tid;
                int i = flat >> 3, jf = (flat & 7) << 2;
                float4 v = make_float4(0.f, 0.f, 0.f, 0.f);
                if (l0 + i < LCONV)
                    v = *(const float4*)(hb + (size_t)(l0 + i + kk) * D_SZ + d0 + jf);
                As[jf + 0][i] = v.x; As[jf + 1][i] = v.y;
                As[jf + 2][i] = v.z; As[jf + 3][i] = v.w;
            }
            #pragma unroll
            for (int p = 0; p < 2; ++p) {
                int flat = p * 256 + tid;
                int j = flat >> 4, cf = (flat & 15) << 2;
                float4 v = make_float4(0.f, 0.f, 0.f, 0.f);
                if (c0 + cf <= CH - 1)
                    v = *(const float4*)(w1t + (size_t)kk * 1024 * CHP +
                                         (size_t)(d0 + j) * CHP + c0 + cf);
                *(float4*)&Bs[j][cf] = v;
            }
            __syncthreads();
            #pragma unroll
            for (int j = 0; j < 32; ++j) {
                float4 a  = *(const float4*)&As[j][ti * 4];
                float4 bb = *(const float4*)&Bs[j][tj * 4];
                float av[4] = {a.x, a.y, a.z, a.w};
                float bv[4] = {bb.x, bb.y, bb.z, bb.w};
                #pragma unroll
                for (int r = 0; r < 4; ++r)
                    #pragma unroll
                    for (int c = 0; c < 4; ++c)
                        acc[r][c] += av[r] * bv[c];
            }
            __syncthreads();
        }
    }

    float part[4];
    #pragma unroll
    for (int r = 0; r < 4; ++r) {
        float p = 0.f;
        #pragma unroll
        for (int c4 = 0; c4 < 4; ++c4) {
            int c = c0 + tj * 4 + c4;
            if (c < CH) {
                float h = acc[r][c4] + b1[c];
                if (h > 0.0f) p += h * w2[c];
            }
        }
        part[r] = p;
    }
    __syncthreads();
    float (*redm)[17] = (float (*)[17])&As[0][0];
    #pragma unroll
    for (int r = 0; r < 4; ++r) redm[ti * 4 + r][tj] = part[r];
    __syncthreads();
    if (tid < 64) {
        float ssum = 0.f;
        #pragma unroll
        for (int t = 0; t < 16; ++t) ssum += redm[tid][t];
        if (l0 + tid < LCONV)
            atomicAdd(&logits[b * LCONV + l0 + tid], ssum);
    }
}

// ---------------------------------------------------------------------------
// Boundary scan: hard bits, segment starts, per-token segment ids,
// short_mask, scalar outputs.
// ---------------------------------------------------------------------------
__global__ void boundary_scan_kernel(const float* __restrict__ logits,
                                     const float* __restrict__ amask,
                                     int* __restrict__ segstart,
                                     int* __restrict__ segid,
                                     float* __restrict__ out_nb,
                                     float* __restrict__ out_tp,
                                     float* __restrict__ short_mask) {
    const int b = blockIdx.x, tid = threadIdx.x;
    __shared__ int sdata[256];
    __shared__ int s_len, s_total;

    int cnt = 0;
    #pragma unroll
    for (int j = 0; j < 8; ++j) {
        int l = tid * 8 + j;
        cnt += (amask[b * L_SZ + l] > 0.5f) ? 1 : 0;
    }
    sdata[tid] = cnt; __syncthreads();
    for (int off = 128; off > 0; off >>= 1) {
        if (tid < off) sdata[tid] += sdata[tid + off];
        __syncthreads();
    }
    if (tid == 0) s_len = sdata[0];
    __syncthreads();
    const int len = s_len;

    int bits[8]; int tsum = 0;
    #pragma unroll
    for (int j = 0; j < 8; ++j) {
        int l = tid * 8 + j;
        int h = 0;
        if (l >= 2 && l < len) h = (logits[b * LCONV + (l - 2)] > 0.0f) ? 1 : 0;
        if (len < L_SZ && l == len - 1) h = 1;
        bits[j] = h; tsum += h;
    }
    __syncthreads();
    sdata[tid] = tsum; __syncthreads();
    for (int off = 1; off < 256; off <<= 1) {
        int v = (tid >= off) ? sdata[tid - off] : 0;
        __syncthreads();
        sdata[tid] += v;
        __syncthreads();
    }
    const int texcl = sdata[tid] - tsum;
    if (tid == 255) s_total = sdata[255];
    __syncthreads();
    const int total = s_total;

    for (int s = tid; s <= NSEG; s += 256)
        segstart[b * (NSEG + 1) + s] = (s == 0) ? 0 : len;
    __syncthreads();
    int run = texcl;
    #pragma unroll
    for (int j = 0; j < 8; ++j) {
        int l = tid * 8 + j;
        int sv = -1;
        if (l < len && run < NSEG) sv = run;
        segid[b * L_SZ + l] = sv;
        if (bits[j]) {
            if (run + 1 <= NSEG) segstart[b * (NSEG + 1) + run + 1] = l + 1;
            run++;
        }
    }

    if (tid == 0) {
        atomicAdd(out_nb, (float)total);
        atomicAdd(out_tp, (float)len);
    }
    for (int s = tid; s < NSEG; s += 256)
        short_mask[b * NSEG + s] = (s < total) ? 1.0f : 0.0f;
}

// ---------------------------------------------------------------------------
// Pool accumulate: flat over tokens, run-accumulate, atomic flush per run.
// grid (32 chunks, 8 b) x 256 threads; wave dq, lane -> d-float4.
// ---------------------------------------------------------------------------
__global__ __launch_bounds__(256) void pool_accum_kernel(
        const float* __restrict__ hidden, const int* __restrict__ segid,
        float* __restrict__ pooled) {
    const int chunk = blockIdx.x, b = blockIdx.y;
    const int tid = threadIdx.x;
    const int dq = tid >> 6, lane = tid & 63;
    const int d0 = dq * 256 + lane * 4;
    const int lbase = chunk * 64;
    const float* hb = hidden + (size_t)b * L_SZ * D_SZ + d0;
    const int* sg = segid + b * L_SZ + lbase;
    float4 acc = make_float4(0.f, 0.f, 0.f, 0.f);
    int cur = -1;
    for (int t = 0; t < 64; ++t) {
        int sid = sg[t];
        if (sid != cur) {
            if (cur >= 0) {
                float* dst = pooled + ((size_t)(b * NSEG + cur)) * D_SZ + d0;
                atomicAdd(dst + 0, acc.x); atomicAdd(dst + 1, acc.y);
                atomicAdd(dst + 2, acc.z); atomicAdd(dst + 3, acc.w);
            }
            acc = make_float4(0.f, 0.f, 0.f, 0.f);
            cur = sid;
        }
        if (sid >= 0) {
            float4 v = *(const float4*)(hb + (size_t)(lbase + t) * D_SZ);
            acc.x += v.x; acc.y += v.y; acc.z += v.z; acc.w += v.w;
        }
    }
    if (cur >= 0) {
        float* dst = pooled + ((size_t)(b * NSEG + cur)) * D_SZ + d0;
        atomicAdd(dst + 0, acc.x); atomicAdd(dst + 1, acc.y);
        atomicAdd(dst + 2, acc.z); atomicAdd(dst + 3, acc.w);
    }
}

// ---------------------------------------------------------------------------
// Pool finalize: divide by count, add sinusoidal PE.
// ---------------------------------------------------------------------------
__global__ __launch_bounds__(256) void pool_final_kernel(
        float* __restrict__ pooled, const int* __restrict__ segstart) {
    const int s = blockIdx.x, b = blockIdx.y, tid = threadIdx.x;
    const int l0 = segstart[b * (NSEG + 1) + s];
    const int l1 = segstart[b * (NSEG + 1) + s + 1];
    const float inv = 1.0f / ((float)(l1 - l0) + 1e-9f);
    const int d0 = tid * 4;
    size_t o = ((size_t)(b * NSEG + s)) * D_SZ + d0;
    float4 v = *(float4*)(pooled + o);
    const float ce = -9.210340371976184f / 512.0f;
    const int i = d0 >> 1;
    const float a0 = (float)s * expf(ce * (float)i);
    const float a1 = (float)s * expf(ce * (float)(i + 1));
    float4 out;
    out.x = v.x * inv + sinf(a0);
    out.y = v.y * inv + cosf(a0);
    out.z = v.z * inv + sinf(a1);
    out.w = v.w * inv + cosf(a1);
    *(float4*)(pooled + o) = out;
}

// ---------------------------------------------------------------------------
extern "C" void kernel_launch(void* const* d_in, const int* in_sizes, int n_in,
                              void* d_out, int out_size, void* d_ws, size_t ws_size,
                              hipStream_t stream) {
    const float* hidden = (const float*)d_in[0];
    const float* amask  = (const float*)d_in[1];
    const float* w1     = (const float*)d_in[2];
    const float* b1     = (const float*)d_in[3];
    const float* w2     = (const float*)d_in[4];
    const float* b2     = (const float*)d_in[5];

    float* out    = (float*)d_out;
    float* pooled = out;
    float* nb     = out + POOLED_N;
    float* tp     = nb + 1;
    float* smask  = out + POOLED_N + 2;

    // zero pooled + scalars (short_mask is fully overwritten by scan)
    hipMemsetAsync(d_out, 0, (size_t)(POOLED_N + 2) * sizeof(float), stream);

    const size_t HID_E = (size_t)B_SZ * L_SZ * D_SZ;           // 16,777,216
    // MFMA-path workspace layout
    const size_t OFF_HID_HI   = 0;
    const size_t OFF_HID_LO   = OFF_HID_HI + HID_E * 2;        // 33,554,432
    const size_t OFF_W1B_HI   = OFF_HID_LO + HID_E * 2;        // 67,108,864
    const size_t OFF_W1B_LO   = OFF_W1B_HI + (size_t)CP * KDIM * 2;
    const size_t OFF_LOGITS   = OFF_W1B_LO + (size_t)CP * KDIM * 2;
    const size_t OFF_SEGSTART = OFF_LOGITS + (size_t)B_SZ * LCONV * 4;
    const size_t OFF_SEGID    = OFF_SEGSTART + (size_t)B_SZ * (NSEG + 1) * 4;
    const size_t NEED_MFMA    = OFF_SEGID + (size_t)B_SZ * L_SZ * 4;

    if (ws_size >= NEED_MFMA) {
        ushort_t* hid_hi = (ushort_t*)((char*)d_ws + OFF_HID_HI);
        ushort_t* hid_lo = (ushort_t*)((char*)d_ws + OFF_HID_LO);
        ushort_t* w1b_hi = (ushort_t*)((char*)d_ws + OFF_W1B_HI);
        ushort_t* w1b_lo = (ushort_t*)((char*)d_ws + OFF_W1B_LO);
        float*    logits = (float*)((char*)d_ws + OFF_LOGITS);
        int*      segst  = (int*)((char*)d_ws + OFF_SEGSTART);
        int*      segid  = (int*)((char*)d_ws + OFF_SEGID);

        convert_hidden_kernel<<<(int)(HID_E / 4 / 256), 256, 0, stream>>>(hidden, hid_hi, hid_lo);
        convert_w1_kernel<<<(CP * KDIM) / 256, 256, 0, stream>>>(w1, b2, w1b_hi, w1b_lo, logits);
        conv_mfma_kernel<<<dim3(6, 16, B_SZ), 256, 0, stream>>>(
            hid_hi, hid_lo, w1b_hi, w1b_lo, b1, w2, logits);
        boundary_scan_kernel<<<B_SZ, 256, 0, stream>>>(logits, amask, segst, segid, nb, tp, smask);
        pool_accum_kernel<<<dim3(32, B_SZ), 256, 0, stream>>>(hidden, segid, pooled);
        pool_final_kernel<<<dim3(NSEG, B_SZ), 256, 0, stream>>>(pooled, segst);
    } else {
        // fallback: fp32 GEMM path (round-1)
        float* w1t    = (float*)d_ws;                               // 3*1024*344 f
        float* logits = w1t + 3 * 1024 * CHP;                       // 8*2046 f
        int*   segst  = (int*)(logits + B_SZ * LCONV);              // 8*513
        int*   segid  = segst + B_SZ * (NSEG + 1);                  // 8*2048

        init_kernel<<<(3 * 1024 * CHP + 255) / 256, 256, 0, stream>>>(w1, b2, w1t, logits);
        conv_gemm_kernel<<<dim3(32, 6, B_SZ), 256, 0, stream>>>(hidden, w1t, b1, w2, logits);
        boundary_scan_kernel<<<B_SZ, 256, 0, stream>>>(logits, amask, segst, segid, nb, tp, smask);
        pool_accum_kernel<<<dim3(32, B_SZ), 256, 0, stream>>>(hidden, segid, pooled);
        pool_final_kernel<<<dim3(NSEG, B_SZ), 256, 0, stream>>>(pooled, segst);
    }
}

// Round 3
// 260.194 us; speedup vs baseline: 4.7037x; 1.5333x over previous
//
#include <hip/hip_runtime.h>
#include <hip/hip_bf16.h>
#include <cmath>

// Problem constants
#define B_SZ 8
#define L_SZ 2048
#define D_SZ 1024
#define CH 341
#define CP 384               // padded channel dim (4 x 96)
#define LCONV 2046           // L - KERNEL + 1
#define NSEG 512
#define KDIM 3072            // 3 * 1024 folded conv K

#define POOLED_N (B_SZ * NSEG * D_SZ)

typedef _Float16 f16x8 __attribute__((ext_vector_type(8)));
typedef float f32x4 __attribute__((ext_vector_type(4)));

__device__ __forceinline__ void gl_lds16(const void* g, void* l) {
    __builtin_amdgcn_global_load_lds(
        (const __attribute__((address_space(1))) unsigned int*)g,
        (__attribute__((address_space(3))) unsigned int*)l, 16, 0, 0);
}

// ---------------------------------------------------------------------------
// Convert hidden fp32 -> fp16 (single copy; fixup kernel guarantees sign
// correctness of thresholded logits, so one fp16 pass suffices)
// ---------------------------------------------------------------------------
__global__ __launch_bounds__(256) void convert_hidden_kernel(
        const float* __restrict__ hidden, _Float16* __restrict__ hid16) {
    size_t idx = (size_t)blockIdx.x * 256 + threadIdx.x;   // 8 elems / thread
    float4 v0 = ((const float4*)hidden)[idx * 2];
    float4 v1 = ((const float4*)hidden)[idx * 2 + 1];
    f16x8 o;
    o[0] = (_Float16)v0.x; o[1] = (_Float16)v0.y;
    o[2] = (_Float16)v0.z; o[3] = (_Float16)v0.w;
    o[4] = (_Float16)v1.x; o[5] = (_Float16)v1.y;
    o[6] = (_Float16)v1.z; o[7] = (_Float16)v1.w;
    ((f16x8*)hid16)[idx] = o;
}

// ---------------------------------------------------------------------------
// Convert w1 (Ch,D,K) -> bpack[c][k'=kk*1024+d] fp16, c padded to 384 with
// zeros. Also init logits to b2.
// ---------------------------------------------------------------------------
__global__ __launch_bounds__(256) void convert_w1_kernel(
        const float* __restrict__ w1, const float* __restrict__ b2,
        _Float16* __restrict__ bpack, float* __restrict__ logits) {
    int idx = blockIdx.x * 256 + threadIdx.x;   // < 384*3072
    int c = idx / KDIM;
    int kp = idx - c * KDIM;
    int kk = kp >> 10, d = kp & 1023;
    float v = (c < CH) ? w1[((size_t)c * 1024 + d) * 3 + kk] : 0.0f;
    bpack[idx] = (_Float16)v;
    if (idx < B_SZ * LCONV) logits[idx] = b2[0];
}

// ---------------------------------------------------------------------------
// Single-pass fp16 MFMA conv GEMM.
// Per batch: M=2046(l) x N=384(c) x K=3072.  A[l][k'] = hid16_flat[l*1024+k']
// (folded conv = shifted-row view, a plain linear K walk).
// Tile 128 l x 96 c, BK=64, 4 waves, wave-tile 64x48 (4x3 of 16x16x32 frags)
// -> 24 MFMAs (~116 cyc) per barrier, 7 gl_lds16 per thread per step.
// Grid (4,16,8) = 512 blocks = exactly 2 blocks/CU.
// LDS in fragment order -> conflict-free ds_read_b128.
// Fused epilogue: relu(h+b1)*w2 reduced over c, atomicAdd into logits.
// ---------------------------------------------------------------------------
#define LDS_B_OFF 16384

__global__ __launch_bounds__(256, 2) void conv_mfma_kernel(
        const _Float16* __restrict__ hid16, const _Float16* __restrict__ bpack,
        const float* __restrict__ b1, const float* __restrict__ w2,
        float* __restrict__ logits) {
    const int nt = blockIdx.x;           // 0..3
    const int mt = blockIdx.y;           // 0..15
    const int b  = blockIdx.z;
    const int l0 = mt * 128;
    const int n0 = nt * 96;
    const int tid = threadIdx.x;
    const int wave = tid >> 6, lane = tid & 63;
    const int wm = wave & 1, wn = wave >> 1;
    const int quad = lane >> 4, l16 = lane & 15;

    __shared__ __align__(16) char lds[28672];   // A 16K + B 12K

    const _Float16* hb = hid16 + (size_t)b * L_SZ * D_SZ;

    // A staging source pointers: 1024 entries (2 kc x 512), 4 per thread.
    // entry e (within kc): i=e>>6, m=i*16+(e&15), koff=((e>>4)&3)*8
    const _Float16* pa[4];
    #pragma unroll
    for (int p = 0; p < 4; ++p) {
        int f = p * 256 + tid;
        int kc = f >> 9, e = f & 511;
        int m = ((e >> 6) << 4) + (e & 15);
        int koff = ((e >> 4) & 3) * 8;
        int l = l0 + m; if (l > LCONV - 1) l = LCONV - 1;
        pa[p] = hb + (size_t)l * 1024 + kc * 32 + koff;
    }
    // B staging: 768 entries (2 kc x 384), 3 per thread.
    const _Float16* pb[3];
    #pragma unroll
    for (int p = 0; p < 3; ++p) {
        int f = p * 256 + tid;
        int kc = (f >= 384) ? 1 : 0, e = f - kc * 384;
        int n = ((e >> 6) << 4) + (e & 15);
        int koff = ((e >> 4) & 3) * 8;
        pb[p] = bpack + (size_t)(n0 + n) * KDIM + kc * 32 + koff;
    }

    f32x4 acc[4][3] = {};

    for (int s = 0; s < KDIM / 64; ++s) {
        #pragma unroll
        for (int p = 0; p < 4; ++p)
            gl_lds16(pa[p], lds + (p * 256 + wave * 64) * 16);
        #pragma unroll
        for (int p = 0; p < 3; ++p)
            gl_lds16(pb[p], lds + LDS_B_OFF + (p * 256 + wave * 64) * 16);
        #pragma unroll
        for (int p = 0; p < 4; ++p) pa[p] += 64;
        #pragma unroll
        for (int p = 0; p < 3; ++p) pb[p] += 64;
        __syncthreads();

        #pragma unroll
        for (int kc = 0; kc < 2; ++kc) {
            f16x8 a[4], bb[3];
            #pragma unroll
            for (int ii = 0; ii < 4; ++ii)
                a[ii] = *(const f16x8*)(lds + (kc * 512 + (wm * 4 + ii) * 64 + lane) * 16);
            #pragma unroll
            for (int jj = 0; jj < 3; ++jj)
                bb[jj] = *(const f16x8*)(lds + LDS_B_OFF + (kc * 384 + (wn * 3 + jj) * 64 + lane) * 16);
            #pragma unroll
            for (int ii = 0; ii < 4; ++ii)
                #pragma unroll
                for (int jj = 0; jj < 3; ++jj)
                    acc[ii][jj] = __builtin_amdgcn_mfma_f32_16x16x32_f16(
                        a[ii], bb[jj], acc[ii][jj], 0, 0, 0);
        }
        __syncthreads();
    }

    // --- epilogue: relu(acc + b1)*w2, reduce over c, atomic into logits ---
    float cb1[3], cw2[3];
    #pragma unroll
    for (int jj = 0; jj < 3; ++jj) {
        int ch = n0 + wn * 48 + jj * 16 + l16;
        bool v = ch < CH;
        cb1[jj] = v ? b1[ch] : 0.0f;
        cw2[jj] = v ? w2[ch] : 0.0f;
    }
    float* red = (float*)lds;   // [128][2]
    #pragma unroll
    for (int ii = 0; ii < 4; ++ii)
        #pragma unroll
        for (int r = 0; r < 4; ++r) {
            float P = 0.0f;
            #pragma unroll
            for (int jj = 0; jj < 3; ++jj) {
                float h = acc[ii][jj][r] + cb1[jj];
                if (h > 0.0f) P += h * cw2[jj];
            }
            P += __shfl_xor(P, 1);
            P += __shfl_xor(P, 2);
            P += __shfl_xor(P, 4);
            P += __shfl_xor(P, 8);
            if (l16 == 0)
                red[(wm * 64 + ii * 16 + quad * 4 + r) * 2 + wn] = P;
        }
    __syncthreads();
    if (tid < 128) {
        int l = l0 + tid;
        if (l < LCONV)
            atomicAdd(&logits[b * LCONV + l], red[tid * 2] + red[tid * 2 + 1]);
    }
}

// ---------------------------------------------------------------------------
// Exact fp32 fixup: any |logit| < 0.02 (>>50 sigma of fp16 GEMM error) gets
// recomputed exactly from hidden/w1 in fp32. Expected flagged: <1 position.
// ---------------------------------------------------------------------------
__global__ __launch_bounds__(256) void fixup_kernel(
        const float* __restrict__ hidden, const float* __restrict__ w1,
        const float* __restrict__ b1, const float* __restrict__ w2,
        const float* __restrict__ b2, float* __restrict__ logits) {
    const int b = blockIdx.y, l0 = blockIdx.x * 64, tid = threadIdx.x;
    __shared__ float hrow[3 * 1024];
    __shared__ float sred[256];
    __shared__ int flags[64];
    __shared__ int nflag;
    if (tid == 0) nflag = 0;
    __syncthreads();
    if (tid < 64) {
        int l = l0 + tid;
        if (l < LCONV) {
            float v = logits[b * LCONV + l];
            if (fabsf(v) < 0.02f) { int k = atomicAdd(&nflag, 1); flags[k] = l; }
        }
    }
    __syncthreads();
    const int nf = nflag;
    for (int fi = 0; fi < nf; ++fi) {
        const int l = flags[fi];
        // rows l..l+2 of hidden are 3072 contiguous floats
        for (int t = tid; t < 3072; t += 256)
            hrow[t] = hidden[((size_t)b * L_SZ + l) * 1024 + t];
        __syncthreads();
        float tot = 0.0f;
        for (int c = tid; c < CH; c += 256) {
            const float* wr = w1 + (size_t)c * 3072;
            float dot = 0.0f;
            for (int d = 0; d < 1024; ++d)
                dot += hrow[d] * wr[d * 3] + hrow[1024 + d] * wr[d * 3 + 1]
                     + hrow[2048 + d] * wr[d * 3 + 2];
            float h = dot + b1[c];
            if (h > 0.0f) tot += h * w2[c];
        }
        sred[tid] = tot; __syncthreads();
        for (int off = 128; off > 0; off >>= 1) {
            if (tid < off) sred[tid] += sred[tid + off];
            __syncthreads();
        }
        if (tid == 0) logits[b * LCONV + l] = sred[0] + b2[0];
        __syncthreads();
    }
}

// ---------------------------------------------------------------------------
// Boundary scan: hard bits, segment starts, per-token segment ids,
// short_mask, scalar outputs.
// ---------------------------------------------------------------------------
__global__ void boundary_scan_kernel(const float* __restrict__ logits,
                                     const float* __restrict__ amask,
                                     int* __restrict__ segstart,
                                     int* __restrict__ segid,
                                     float* __restrict__ out_nb,
                                     float* __restrict__ out_tp,
                                     float* __restrict__ short_mask) {
    const int b = blockIdx.x, tid = threadIdx.x;
    __shared__ int sdata[256];
    __shared__ int s_len, s_total;

    int cnt = 0;
    #pragma unroll
    for (int j = 0; j < 8; ++j) {
        int l = tid * 8 + j;
        cnt += (amask[b * L_SZ + l] > 0.5f) ? 1 : 0;
    }
    sdata[tid] = cnt; __syncthreads();
    for (int off = 128; off > 0; off >>= 1) {
        if (tid < off) sdata[tid] += sdata[tid + off];
        __syncthreads();
    }
    if (tid == 0) s_len = sdata[0];
    __syncthreads();
    const int len = s_len;

    int bits[8]; int tsum = 0;
    #pragma unroll
    for (int j = 0; j < 8; ++j) {
        int l = tid * 8 + j;
        int h = 0;
        if (l >= 2 && l < len) h = (logits[b * LCONV + (l - 2)] > 0.0f) ? 1 : 0;
        if (len < L_SZ && l == len - 1) h = 1;
        bits[j] = h; tsum += h;
    }
    __syncthreads();
    sdata[tid] = tsum; __syncthreads();
    for (int off = 1; off < 256; off <<= 1) {
        int v = (tid >= off) ? sdata[tid - off] : 0;
        __syncthreads();
        sdata[tid] += v;
        __syncthreads();
    }
    const int texcl = sdata[tid] - tsum;
    if (tid == 255) s_total = sdata[255];
    __syncthreads();
    const int total = s_total;

    for (int s = tid; s <= NSEG; s += 256)
        segstart[b * (NSEG + 1) + s] = (s == 0) ? 0 : len;
    __syncthreads();
    int run = texcl;
    #pragma unroll
    for (int j = 0; j < 8; ++j) {
        int l = tid * 8 + j;
        int sv = -1;
        if (l < len && run < NSEG) sv = run;
        segid[b * L_SZ + l] = sv;
        if (bits[j]) {
            if (run + 1 <= NSEG) segstart[b * (NSEG + 1) + run + 1] = l + 1;
            run++;
        }
    }

    if (tid == 0) {
        atomicAdd(out_nb, (float)total);
        atomicAdd(out_tp, (float)len);
    }
    for (int s = tid; s < NSEG; s += 256)
        short_mask[b * NSEG + s] = (s < total) ? 1.0f : 0.0f;
}

// ---------------------------------------------------------------------------
// Pool accumulate: 16-token chunks, thread = 4 d over the chunk, atomic flush
// per segment run. Grid (128,8) = 1024 blocks x 256 threads.
// ---------------------------------------------------------------------------
__global__ __launch_bounds__(256) void pool_accum_kernel(
        const float* __restrict__ hidden, const int* __restrict__ segid,
        float* __restrict__ pooled) {
    const int chunk = blockIdx.x, b = blockIdx.y;
    const int tid = threadIdx.x;
    const int d0 = tid * 4;
    const int lbase = chunk * 16;
    const float* hb = hidden + (size_t)b * L_SZ * D_SZ + d0;
    const int* sg = segid + b * L_SZ + lbase;
    float4 acc = make_float4(0.f, 0.f, 0.f, 0.f);
    int cur = -1;
    #pragma unroll
    for (int t = 0; t < 16; ++t) {
        int sid = sg[t];
        if (sid != cur) {
            if (cur >= 0) {
                float* dst = pooled + ((size_t)(b * NSEG + cur)) * D_SZ + d0;
                atomicAdd(dst + 0, acc.x); atomicAdd(dst + 1, acc.y);
                atomicAdd(dst + 2, acc.z); atomicAdd(dst + 3, acc.w);
            }
            acc = make_float4(0.f, 0.f, 0.f, 0.f);
            cur = sid;
        }
        if (sid >= 0) {
            float4 v = *(const float4*)(hb + (size_t)(lbase + t) * D_SZ);
            acc.x += v.x; acc.y += v.y; acc.z += v.z; acc.w += v.w;
        }
    }
    if (cur >= 0) {
        float* dst = pooled + ((size_t)(b * NSEG + cur)) * D_SZ + d0;
        atomicAdd(dst + 0, acc.x); atomicAdd(dst + 1, acc.y);
        atomicAdd(dst + 2, acc.z); atomicAdd(dst + 3, acc.w);
    }
}

// ---------------------------------------------------------------------------
// Pool finalize: divide by count, add sinusoidal PE.
// ---------------------------------------------------------------------------
__global__ __launch_bounds__(256) void pool_final_kernel(
        float* __restrict__ pooled, const int* __restrict__ segstart) {
    const int s = blockIdx.x, b = blockIdx.y, tid = threadIdx.x;
    const int l0 = segstart[b * (NSEG + 1) + s];
    const int l1 = segstart[b * (NSEG + 1) + s + 1];
    const float inv = 1.0f / ((float)(l1 - l0) + 1e-9f);
    const int d0 = tid * 4;
    size_t o = ((size_t)(b * NSEG + s)) * D_SZ + d0;
    float4 v = *(float4*)(pooled + o);
    const float ce = -9.210340371976184f / 512.0f;
    const int i = d0 >> 1;
    const float a0 = (float)s * expf(ce * (float)i);
    const float a1 = (float)s * expf(ce * (float)(i + 1));
    float4 out;
    out.x = v.x * inv + sinf(a0);
    out.y = v.y * inv + cosf(a0);
    out.z = v.z * inv + sinf(a1);
    out.w = v.w * inv + cosf(a1);
    *(float4*)(pooled + o) = out;
}

// ---------------------------------------------------------------------------
extern "C" void kernel_launch(void* const* d_in, const int* in_sizes, int n_in,
                              void* d_out, int out_size, void* d_ws, size_t ws_size,
                              hipStream_t stream) {
    const float* hidden = (const float*)d_in[0];
    const float* amask  = (const float*)d_in[1];
    const float* w1     = (const float*)d_in[2];
    const float* b1     = (const float*)d_in[3];
    const float* w2     = (const float*)d_in[4];
    const float* b2     = (const float*)d_in[5];

    float* out    = (float*)d_out;
    float* pooled = out;
    float* nb     = out + POOLED_N;
    float* tp     = nb + 1;
    float* smask  = out + POOLED_N + 2;

    // zero pooled + scalars (short_mask fully overwritten by scan)
    hipMemsetAsync(d_out, 0, (size_t)(POOLED_N + 2) * sizeof(float), stream);

    const size_t HID_E = (size_t)B_SZ * L_SZ * D_SZ;           // 16,777,216
    const size_t OFF_HID16    = 0;
    const size_t OFF_BPACK    = OFF_HID16 + HID_E * 2;                 // 32 MB
    const size_t OFF_LOGITS   = OFF_BPACK + (size_t)CP * KDIM * 2;     // +2.25 MB
    const size_t OFF_SEGSTART = OFF_LOGITS + (size_t)B_SZ * LCONV * 4;
    const size_t OFF_SEGID    = OFF_SEGSTART + (size_t)B_SZ * (NSEG + 1) * 4;

    _Float16* hid16  = (_Float16*)((char*)d_ws + OFF_HID16);
    _Float16* bpack  = (_Float16*)((char*)d_ws + OFF_BPACK);
    float*    logits = (float*)((char*)d_ws + OFF_LOGITS);
    int*      segst  = (int*)((char*)d_ws + OFF_SEGSTART);
    int*      segid  = (int*)((char*)d_ws + OFF_SEGID);

    convert_hidden_kernel<<<(int)(HID_E / 8 / 256), 256, 0, stream>>>(hidden, hid16);
    convert_w1_kernel<<<(CP * KDIM) / 256, 256, 0, stream>>>(w1, b2, bpack, logits);
    conv_mfma_kernel<<<dim3(4, 16, B_SZ), 256, 0, stream>>>(hid16, bpack, b1, w2, logits);
    fixup_kernel<<<dim3(32, B_SZ), 256, 0, stream>>>(hidden, w1, b1, w2, b2, logits);
    boundary_scan_kernel<<<B_SZ, 256, 0, stream>>>(logits, amask, segst, segid, nb, tp, smask);
    pool_accum_kernel<<<dim3(128, B_SZ), 256, 0, stream>>>(hidden, segid, pooled);
    pool_final_kernel<<<dim3(NSEG, B_SZ), 256, 0, stream>>>(pooled, segst);
}